// Round 8
// baseline (428.319 us; speedup 1.0000x reference)
//
#include <hip/hip_runtime.h>
#include <hip/hip_cooperative_groups.h>
#include <math.h>

namespace cg = cooperative_groups;

// Problem constants
#define BSZ    2
#define LSEQ   2048
#define DI     2048
#define DSTATE 8
#define DTRANK 256
#define KXP    (DTRANK + 2 * DSTATE)   // 272
#define NPAD   288                     // KXP padded to 18*16 for MFMA tiles
#define NC     64                      // scan chunks
#define CL     (LSEQ / NC)             // 32
#define KSPLIT 8                       // gemm1 K-splits (bf16 partials)
#define KCHUNK (DI / KSPLIT)           // 256
#define SCAN_BLOCKS (BSZ * NC * 8)     // 1024

#define NWXP (288u * 2048u)            // 589824 (padded)
#define NWX  (272u * 2048u)            // 557056 (real)
#define NWDT (2048u * 256u)            // 524288

typedef __attribute__((ext_vector_type(8))) short bf16x8;
typedef __attribute__((ext_vector_type(4))) float f32x4;

static __device__ __forceinline__ unsigned short f2bf(float f) {
    unsigned u = __float_as_uint(f);
    u += 0x7fff + ((u >> 16) & 1);   // round-to-nearest-even
    return (unsigned short)(u >> 16);
}
static __device__ __forceinline__ float bf2f(unsigned short s) {
    return __uint_as_float((unsigned)s << 16);
}

static __device__ __forceinline__ float softplus_fast(float z) {
    const float e = __expf(-fabsf(z));
    return fmaxf(z, 0.0f) + __logf(1.0f + e);
}

// ---------------------------------------------------------------------------
// Convert weight matrices to bf16.
// ---------------------------------------------------------------------------
__global__ __launch_bounds__(256) void convert_w(const float* __restrict__ Wx,
                                                 const float* __restrict__ Wdt,
                                                 unsigned short* __restrict__ Wxb,
                                                 unsigned short* __restrict__ Wdtb) {
    const unsigned tid = blockIdx.x * 256 + threadIdx.x;
    const unsigned i4 = tid * 4;
    float4 v;
    unsigned short* dst;
    unsigned j;
    if (i4 < NWXP) {
        j = i4;
        v = (j < NWX) ? *(const float4*)&Wx[j] : make_float4(0.f, 0.f, 0.f, 0.f);
        dst = Wxb;
    } else {
        j = i4 - NWXP;
        if (j >= NWDT) return;
        v = *(const float4*)&Wdt[j];
        dst = Wdtb;
    }
    ushort4 o;
    o.x = f2bf(v.x); o.y = f2bf(v.y); o.z = f2bf(v.z); o.w = f2bf(v.w);
    *(ushort4*)&dst[j] = o;
}

// ---------------------------------------------------------------------------
// GEMM1 (MFMA, split-K, LDS-staged, bf16 partials):
//   partb[ks][4096][288] = bf16( x[., ks-chunk] @ Wxb^T )
// BM=64, BN=288(full), BK=32. grid (64 Mtiles, 8 Ksplits) = 512 blocks.
// ---------------------------------------------------------------------------
#define G1RS 40
__global__ __launch_bounds__(256) void gemm1_mfma(const float* __restrict__ x,
                                                  const unsigned short* __restrict__ Wxb,
                                                  unsigned short* __restrict__ partb) {
    __shared__ __align__(16) unsigned short As[64 * G1RS];
    __shared__ __align__(16) unsigned short Bs[288 * G1RS];
    const int mt   = blockIdx.x;
    const int ks   = blockIdx.y;
    const int t    = threadIdx.x;
    const int wave = t >> 6;
    const int lane = t & 63;
    const int quad = lane >> 4;
    const int r    = lane & 15;
    const int rh   = wave >> 1;
    const int nh   = wave & 1;
    const int m0   = mt * 64;

    const int arow = t >> 2;
    const int aoff = (t & 3) * 8;

    f32x4 acc[2][9];
#pragma unroll
    for (int f = 0; f < 2; f++)
#pragma unroll
        for (int n = 0; n < 9; n++) acc[f][n] = (f32x4)(0.0f);

    const int kbeg = ks * KCHUNK;
    for (int k0 = kbeg; k0 < kbeg + KCHUNK; k0 += 32) {
        const float4 a0 = *(const float4*)&x[(size_t)(m0 + arow) * DI + k0 + aoff];
        const float4 a1 = *(const float4*)&x[(size_t)(m0 + arow) * DI + k0 + aoff + 4];
        bf16x8 bstage[5];
#pragma unroll
        for (int j = 0; j < 5; j++) {
            const int i = t + j * 256;
            if (i < 1152)
                bstage[j] = *(const bf16x8*)&Wxb[(size_t)(i >> 2) * DI + k0 + (i & 3) * 8];
        }
        __syncthreads();
        bf16x8 av;
        av[0] = (short)f2bf(a0.x); av[1] = (short)f2bf(a0.y);
        av[2] = (short)f2bf(a0.z); av[3] = (short)f2bf(a0.w);
        av[4] = (short)f2bf(a1.x); av[5] = (short)f2bf(a1.y);
        av[6] = (short)f2bf(a1.z); av[7] = (short)f2bf(a1.w);
        *(bf16x8*)&As[arow * G1RS + aoff] = av;
#pragma unroll
        for (int j = 0; j < 5; j++) {
            const int i = t + j * 256;
            if (i < 1152)
                *(bf16x8*)&Bs[(i >> 2) * G1RS + (i & 3) * 8] = bstage[j];
        }
        __syncthreads();

        bf16x8 af[2], bf[9];
#pragma unroll
        for (int f = 0; f < 2; f++)
            af[f] = *(const bf16x8*)&As[(rh * 32 + f * 16 + r) * G1RS + quad * 8];
#pragma unroll
        for (int nf = 0; nf < 9; nf++)
            bf[nf] = *(const bf16x8*)&Bs[(nh * 144 + nf * 16 + r) * G1RS + quad * 8];
#pragma unroll
        for (int f = 0; f < 2; f++)
#pragma unroll
            for (int nf = 0; nf < 9; nf++)
                acc[f][nf] = __builtin_amdgcn_mfma_f32_16x16x32_bf16(af[f], bf[nf], acc[f][nf], 0, 0, 0);
    }

    unsigned short* p = partb + (size_t)ks * 4096 * NPAD;
#pragma unroll
    for (int f = 0; f < 2; f++) {
        const int row0 = m0 + rh * 32 + f * 16 + quad * 4;
#pragma unroll
        for (int nf = 0; nf < 9; nf++) {
            const int col = nh * 144 + nf * 16 + r;
#pragma unroll
            for (int i = 0; i < 4; i++)
                p[(size_t)(row0 + i) * NPAD + col] = f2bf(acc[f][nf][i]);
        }
    }
}

// ---------------------------------------------------------------------------
// Reduce split-K bf16 partials -> dtr bf16 [4096][256] (for GEMM2) and
// compact BC fp32 [4096][16] (B_ssm|C_ssm rows for the scan).
// ---------------------------------------------------------------------------
__global__ __launch_bounds__(256) void reduce1(const unsigned short* __restrict__ partb,
                                               unsigned short* __restrict__ dtr,
                                               float* __restrict__ BC) {
    const int tid = blockIdx.x * 256 + threadIdx.x;  // 4096*72
    const int row = tid / 72;
    const int c4  = (tid - row * 72) * 4;
    float4 s = make_float4(0.f, 0.f, 0.f, 0.f);
#pragma unroll
    for (int ks = 0; ks < KSPLIT; ks++) {
        const ushort4 v = *(const ushort4*)&partb[(size_t)ks * 4096 * NPAD + (size_t)row * NPAD + c4];
        s.x += bf2f(v.x); s.y += bf2f(v.y); s.z += bf2f(v.z); s.w += bf2f(v.w);
    }
    if (c4 < DTRANK) {
        ushort4 o;
        o.x = f2bf(s.x); o.y = f2bf(s.y); o.z = f2bf(s.z); o.w = f2bf(s.w);
        *(ushort4*)&dtr[(size_t)row * DTRANK + c4] = o;
    } else if (c4 < KXP) {
        *(float4*)&BC[(size_t)row * 16 + (c4 - DTRANK)] = s;
    }
}

// ---------------------------------------------------------------------------
// GEMM2 (MFMA, LDS-staged): deltab[4096][2048] (bf16)
//   = softplus(dtr @ Wdtb^T + b_dt). K=256, BK=32. 128x128 tile.
// ---------------------------------------------------------------------------
#define G2RS 40
__global__ __launch_bounds__(256, 2) void gemm2_mfma(const unsigned short* __restrict__ dtr,
                                                     const unsigned short* __restrict__ Wdtb,
                                                     const float* __restrict__ bdt,
                                                     unsigned short* __restrict__ deltab) {
    __shared__ __align__(16) unsigned short As[128 * G2RS];
    __shared__ __align__(16) unsigned short Bs[128 * G2RS];
    const int nt   = blockIdx.x;
    const int mt   = blockIdx.y;
    const int t    = threadIdx.x;
    const int wave = t >> 6;
    const int lane = t & 63;
    const int quad = lane >> 4;
    const int r    = lane & 15;
    const int m0 = mt * 128, n0 = nt * 128;
    const int mw = (wave >> 1) * 64, nw = (wave & 1) * 64;

    const int srow = t >> 1;
    const int sc   = (t & 1) * 16;

    f32x4 acc[4][4];
#pragma unroll
    for (int f = 0; f < 4; f++)
#pragma unroll
        for (int g = 0; g < 4; g++) acc[f][g] = (f32x4)(0.0f);

    for (int k0 = 0; k0 < DTRANK; k0 += 32) {
        const bf16x8 a0 = *(const bf16x8*)&dtr[(size_t)(m0 + srow) * DTRANK + k0 + sc];
        const bf16x8 a1 = *(const bf16x8*)&dtr[(size_t)(m0 + srow) * DTRANK + k0 + sc + 8];
        const bf16x8 b0 = *(const bf16x8*)&Wdtb[(size_t)(n0 + srow) * DTRANK + k0 + sc];
        const bf16x8 b1 = *(const bf16x8*)&Wdtb[(size_t)(n0 + srow) * DTRANK + k0 + sc + 8];
        __syncthreads();
        *(bf16x8*)&As[srow * G2RS + sc]     = a0;
        *(bf16x8*)&As[srow * G2RS + sc + 8] = a1;
        *(bf16x8*)&Bs[srow * G2RS + sc]     = b0;
        *(bf16x8*)&Bs[srow * G2RS + sc + 8] = b1;
        __syncthreads();

        bf16x8 a[4], b[4];
#pragma unroll
        for (int f = 0; f < 4; f++)
            a[f] = *(const bf16x8*)&As[(mw + f * 16 + r) * G2RS + quad * 8];
#pragma unroll
        for (int g = 0; g < 4; g++)
            b[g] = *(const bf16x8*)&Bs[(nw + g * 16 + r) * G2RS + quad * 8];
#pragma unroll
        for (int f = 0; f < 4; f++)
#pragma unroll
            for (int g = 0; g < 4; g++)
                acc[f][g] = __builtin_amdgcn_mfma_f32_16x16x32_bf16(a[f], b[g], acc[f][g], 0, 0, 0);
    }

#pragma unroll
    for (int f = 0; f < 4; f++) {
        const int row0 = m0 + mw + f * 16 + quad * 4;
#pragma unroll
        for (int g = 0; g < 4; g++) {
            const int col = n0 + nw + g * 16 + r;
            const float bv = bdt[col];
#pragma unroll
            for (int i = 0; i < 4; i++)
                deltab[(size_t)(row0 + i) * DI + col] = f2bf(softplus_fast(acc[f][g][i] + bv));
        }
    }
}

// ---------------------------------------------------------------------------
// Fused scan (cooperative, 1024 blocks x 256), SLIM: ~60 VGPRs so 1024-block
// co-residency has big margin (no per-chunk register stash; Phase C re-reads
// x/deltab from L2/L3).
// ---------------------------------------------------------------------------
__global__ __launch_bounds__(256, 4) void scan_fused(const float* __restrict__ x,
                                                     const unsigned short* __restrict__ deltab,
                                                     const float* __restrict__ BC,
                                                     const float* __restrict__ Alog,
                                                     const float* __restrict__ Dp,
                                                     float* __restrict__ Pb,
                                                     float* __restrict__ Hb,
                                                     float* __restrict__ h0,
                                                     float* __restrict__ y) {
    __shared__ __align__(16) float Ls[CL * 16];    // B|C rows for this chunk
    const int bi   = blockIdx.x;
    const int b    = bi >> 9;
    const int c    = (bi >> 3) & 63;
    const int dblk = bi & 7;
    const int tid  = threadIdx.x;
    const int d    = dblk * 256 + tid;
    const int l0   = c * CL;
    const size_t row0 = (size_t)b * LSEQ + l0;

    // stage BC rows (compact): 32 rows x 16 floats
    if (tid < CL * 4) {
        const int l = tid >> 2, part = (tid & 3) * 4;
        *(float4*)&Ls[l * 16 + part] = *(const float4*)&BC[(row0 + l) * 16 + part];
    }

    float A[8], P[8], H[8];
#pragma unroll
    for (int n = 0; n < 8; n++) {
        A[n] = -__expf(Alog[d * 8 + n]);
        P[n] = 1.f;
        H[n] = 0.f;
    }
    __syncthreads();

    // ---- Phase A: chunk-local scan from 0 ----
    for (int l = 0; l < CL; l++) {
        const size_t row = row0 + l;
        const float dl = bf2f(deltab[row * DI + d]);
        const float xv = x[row * DI + d];
        const float du = dl * xv;
#pragma unroll
        for (int n = 0; n < 8; n++) {
            const float dA = __expf(dl * A[n]);
            H[n] = dA * H[n] + du * Ls[l * 16 + n];
            P[n] *= dA;
        }
    }
    const size_t base = ((size_t)(b * NC + c) * DI + d) * 8;
    *(float4*)&Pb[base]     = make_float4(P[0], P[1], P[2], P[3]);
    *(float4*)&Pb[base + 4] = make_float4(P[4], P[5], P[6], P[7]);
    *(float4*)&Hb[base]     = make_float4(H[0], H[1], H[2], H[3]);
    *(float4*)&Hb[base + 4] = make_float4(H[4], H[5], H[6], H[7]);

    cg::this_grid().sync();

    // ---- Phase B: combine NC summaries per (b,d,n) chain (blocks 0..127) ----
    const int gt = bi * 256 + tid;
    if (gt < BSZ * DI * 8) {
        const int b2  = gt >> 14;
        const int rem = gt & 16383;
        float h = 0.f;
        for (int cc = 0; cc < NC; cc++) {
            const size_t bb = (size_t)(b2 * NC + cc) * (DI * 8) + rem;
            h0[bb] = h;
            h = Pb[bb] * h + Hb[bb];
        }
    }

    cg::this_grid().sync();

    // ---- Phase C: rescan from h0, write y (re-reads x/deltab via L2/L3) ----
    float h[8];
    const float4 h0a = *(const float4*)&h0[base];
    const float4 h0b = *(const float4*)&h0[base + 4];
    h[0] = h0a.x; h[1] = h0a.y; h[2] = h0a.z; h[3] = h0a.w;
    h[4] = h0b.x; h[5] = h0b.y; h[6] = h0b.z; h[7] = h0b.w;
    const float Dpar = Dp[d];

    for (int l = 0; l < CL; l++) {
        const size_t row = row0 + l;
        const float dl = bf2f(deltab[row * DI + d]);
        const float xv = x[row * DI + d];
        const float du = dl * xv;
        float yv = 0.f;
#pragma unroll
        for (int n = 0; n < 8; n++) {
            const float dA = __expf(dl * A[n]);
            h[n] = dA * h[n] + du * Ls[l * 16 + n];
            yv += h[n] * Ls[l * 16 + 8 + n];
        }
        y[row * DI + d] = yv + xv * Dpar;
    }
}

// ---------------------------------------------------------------------------
extern "C" void kernel_launch(void* const* d_in, const int* in_sizes, int n_in,
                              void* d_out, int out_size, void* d_ws, size_t ws_size,
                              hipStream_t stream) {
    const float* x    = (const float*)d_in[0];
    const float* Wx   = (const float*)d_in[1];
    const float* Wdt  = (const float*)d_in[2];
    const float* bdt  = (const float*)d_in[3];
    const float* Alog = (const float*)d_in[4];
    const float* Dp   = (const float*)d_in[5];
    float* y = (float*)d_out;

    // Workspace (float offsets). deltab aliases partb (dead after reduce1).
    float* ws = (float*)d_ws;
    unsigned short* partb  = (unsigned short*)ws;        // 8*4096*288 bf16
    unsigned short* deltab = (unsigned short*)ws;        // alias
    float* BC = ws + 4718592;
    float* Pb = ws + 4784128;
    float* Hb = ws + 6881280;
    float* h0 = ws + 8978432;
    unsigned short* Wxb  = (unsigned short*)(ws + 11075584);
    unsigned short* Wdtb = (unsigned short*)(ws + 11370496);
    unsigned short* dtr  = (unsigned short*)(ws + 11632640);

    dim3 blk(256);
    hipLaunchKernelGGL(convert_w, dim3((NWXP + NWDT) / 4 / 256), blk, 0, stream,
                       Wx, Wdt, Wxb, Wdtb);
    hipLaunchKernelGGL(gemm1_mfma, dim3(64, KSPLIT), blk, 0, stream, x, Wxb, partb);
    hipLaunchKernelGGL(reduce1, dim3(4096 * 72 / 256), blk, 0, stream, partb, dtr, BC);
    hipLaunchKernelGGL(gemm2_mfma, dim3(16, 32), blk, 0, stream, dtr, Wdtb, bdt, deltab);

    const unsigned short* deltab_c = deltab;
    const float* BC_c = BC;
    void* args[] = {(void*)&x, (void*)&deltab_c, (void*)&BC_c, (void*)&Alog, (void*)&Dp,
                    (void*)&Pb, (void*)&Hb, (void*)&h0, (void*)&y};
    hipLaunchCooperativeKernel((void*)scan_fused, dim3(SCAN_BLOCKS), blk, args, 0, stream);
}

// Round 9
// 188.977 us; speedup vs baseline: 2.2665x; 2.2665x over previous
//
#include <hip/hip_runtime.h>
#include <math.h>

// Problem constants
#define BSZ    2
#define LSEQ   2048
#define DI     2048
#define DSTATE 8
#define DTRANK 256
#define KXP    (DTRANK + 2 * DSTATE)   // 272
#define NPAD   288                     // KXP padded to 18*16 for MFMA tiles
#define NC     64                      // scan chunks
#define CL     (LSEQ / NC)             // 32
#define KSPLIT 8                       // gemm1 K-splits (bf16 partials)
#define KCHUNK (DI / KSPLIT)           // 256

#define NWXP (288u * 2048u)            // 589824 (padded)
#define NWX  (272u * 2048u)            // 557056 (real)
#define NWDT (2048u * 256u)            // 524288

typedef __attribute__((ext_vector_type(8))) short bf16x8;
typedef __attribute__((ext_vector_type(4))) float f32x4;

static __device__ __forceinline__ unsigned short f2bf(float f) {
    unsigned u = __float_as_uint(f);
    u += 0x7fff + ((u >> 16) & 1);   // round-to-nearest-even
    return (unsigned short)(u >> 16);
}
static __device__ __forceinline__ float bf2f(unsigned short s) {
    return __uint_as_float((unsigned)s << 16);
}

static __device__ __forceinline__ float softplus_fast(float z) {
    const float e = __expf(-fabsf(z));
    return fmaxf(z, 0.0f) + __logf(1.0f + e);
}

// ---------------------------------------------------------------------------
// Convert weight matrices to bf16.
// ---------------------------------------------------------------------------
__global__ __launch_bounds__(256) void convert_w(const float* __restrict__ Wx,
                                                 const float* __restrict__ Wdt,
                                                 unsigned short* __restrict__ Wxb,
                                                 unsigned short* __restrict__ Wdtb) {
    const unsigned tid = blockIdx.x * 256 + threadIdx.x;
    const unsigned i4 = tid * 4;
    float4 v;
    unsigned short* dst;
    unsigned j;
    if (i4 < NWXP) {
        j = i4;
        v = (j < NWX) ? *(const float4*)&Wx[j] : make_float4(0.f, 0.f, 0.f, 0.f);
        dst = Wxb;
    } else {
        j = i4 - NWXP;
        if (j >= NWDT) return;
        v = *(const float4*)&Wdt[j];
        dst = Wdtb;
    }
    ushort4 o;
    o.x = f2bf(v.x); o.y = f2bf(v.y); o.z = f2bf(v.z); o.w = f2bf(v.w);
    *(ushort4*)&dst[j] = o;
}

// ---------------------------------------------------------------------------
// GEMM1 (MFMA, split-K, LDS-staged, bf16 partials):
//   partb[ks][4096][288] = bf16( x[., ks-chunk] @ Wxb^T )
// BM=64, BN=288(full), BK=32. grid (64 Mtiles, 8 Ksplits) = 512 blocks.
// ---------------------------------------------------------------------------
#define G1RS 40
__global__ __launch_bounds__(256) void gemm1_mfma(const float* __restrict__ x,
                                                  const unsigned short* __restrict__ Wxb,
                                                  unsigned short* __restrict__ partb) {
    __shared__ __align__(16) unsigned short As[64 * G1RS];
    __shared__ __align__(16) unsigned short Bs[288 * G1RS];
    const int mt   = blockIdx.x;
    const int ks   = blockIdx.y;
    const int t    = threadIdx.x;
    const int wave = t >> 6;
    const int lane = t & 63;
    const int quad = lane >> 4;
    const int r    = lane & 15;
    const int rh   = wave >> 1;
    const int nh   = wave & 1;
    const int m0   = mt * 64;

    const int arow = t >> 2;
    const int aoff = (t & 3) * 8;

    f32x4 acc[2][9];
#pragma unroll
    for (int f = 0; f < 2; f++)
#pragma unroll
        for (int n = 0; n < 9; n++) acc[f][n] = (f32x4)(0.0f);

    const int kbeg = ks * KCHUNK;
    for (int k0 = kbeg; k0 < kbeg + KCHUNK; k0 += 32) {
        const float4 a0 = *(const float4*)&x[(size_t)(m0 + arow) * DI + k0 + aoff];
        const float4 a1 = *(const float4*)&x[(size_t)(m0 + arow) * DI + k0 + aoff + 4];
        bf16x8 bstage[5];
#pragma unroll
        for (int j = 0; j < 5; j++) {
            const int i = t + j * 256;
            if (i < 1152)
                bstage[j] = *(const bf16x8*)&Wxb[(size_t)(i >> 2) * DI + k0 + (i & 3) * 8];
        }
        __syncthreads();
        bf16x8 av;
        av[0] = (short)f2bf(a0.x); av[1] = (short)f2bf(a0.y);
        av[2] = (short)f2bf(a0.z); av[3] = (short)f2bf(a0.w);
        av[4] = (short)f2bf(a1.x); av[5] = (short)f2bf(a1.y);
        av[6] = (short)f2bf(a1.z); av[7] = (short)f2bf(a1.w);
        *(bf16x8*)&As[arow * G1RS + aoff] = av;
#pragma unroll
        for (int j = 0; j < 5; j++) {
            const int i = t + j * 256;
            if (i < 1152)
                *(bf16x8*)&Bs[(i >> 2) * G1RS + (i & 3) * 8] = bstage[j];
        }
        __syncthreads();

        bf16x8 af[2], bf[9];
#pragma unroll
        for (int f = 0; f < 2; f++)
            af[f] = *(const bf16x8*)&As[(rh * 32 + f * 16 + r) * G1RS + quad * 8];
#pragma unroll
        for (int nf = 0; nf < 9; nf++)
            bf[nf] = *(const bf16x8*)&Bs[(nh * 144 + nf * 16 + r) * G1RS + quad * 8];
#pragma unroll
        for (int f = 0; f < 2; f++)
#pragma unroll
            for (int nf = 0; nf < 9; nf++)
                acc[f][nf] = __builtin_amdgcn_mfma_f32_16x16x32_bf16(af[f], bf[nf], acc[f][nf], 0, 0, 0);
    }

    unsigned short* p = partb + (size_t)ks * 4096 * NPAD;
#pragma unroll
    for (int f = 0; f < 2; f++) {
        const int row0 = m0 + rh * 32 + f * 16 + quad * 4;
#pragma unroll
        for (int nf = 0; nf < 9; nf++) {
            const int col = nh * 144 + nf * 16 + r;
#pragma unroll
            for (int i = 0; i < 4; i++)
                p[(size_t)(row0 + i) * NPAD + col] = f2bf(acc[f][nf][i]);
        }
    }
}

// ---------------------------------------------------------------------------
// Reduce split-K bf16 partials -> dtr bf16 [4096][256] (for GEMM2) and
// compact BC fp32 [4096][16] (B_ssm|C_ssm rows for the scan).
// ---------------------------------------------------------------------------
__global__ __launch_bounds__(256) void reduce1(const unsigned short* __restrict__ partb,
                                               unsigned short* __restrict__ dtr,
                                               float* __restrict__ BC) {
    const int tid = blockIdx.x * 256 + threadIdx.x;  // 4096*72
    const int row = tid / 72;
    const int c4  = (tid - row * 72) * 4;
    float4 s = make_float4(0.f, 0.f, 0.f, 0.f);
#pragma unroll
    for (int ks = 0; ks < KSPLIT; ks++) {
        const ushort4 v = *(const ushort4*)&partb[(size_t)ks * 4096 * NPAD + (size_t)row * NPAD + c4];
        s.x += bf2f(v.x); s.y += bf2f(v.y); s.z += bf2f(v.z); s.w += bf2f(v.w);
    }
    if (c4 < DTRANK) {
        ushort4 o;
        o.x = f2bf(s.x); o.y = f2bf(s.y); o.z = f2bf(s.z); o.w = f2bf(s.w);
        *(ushort4*)&dtr[(size_t)row * DTRANK + c4] = o;
    } else if (c4 < KXP) {
        *(float4*)&BC[(size_t)row * 16 + (c4 - DTRANK)] = s;
    }
}

// ---------------------------------------------------------------------------
// GEMM2 (MFMA, LDS-staged): deltab[4096][2048] (bf16)
//   = softplus(dtr @ Wdtb^T + b_dt). K=256, BK=32. 128x128 tile.
// ---------------------------------------------------------------------------
#define G2RS 40
__global__ __launch_bounds__(256, 2) void gemm2_mfma(const unsigned short* __restrict__ dtr,
                                                     const unsigned short* __restrict__ Wdtb,
                                                     const float* __restrict__ bdt,
                                                     unsigned short* __restrict__ deltab) {
    __shared__ __align__(16) unsigned short As[128 * G2RS];
    __shared__ __align__(16) unsigned short Bs[128 * G2RS];
    const int nt   = blockIdx.x;
    const int mt   = blockIdx.y;
    const int t    = threadIdx.x;
    const int wave = t >> 6;
    const int lane = t & 63;
    const int quad = lane >> 4;
    const int r    = lane & 15;
    const int m0 = mt * 128, n0 = nt * 128;
    const int mw = (wave >> 1) * 64, nw = (wave & 1) * 64;

    const int srow = t >> 1;
    const int sc   = (t & 1) * 16;

    f32x4 acc[4][4];
#pragma unroll
    for (int f = 0; f < 4; f++)
#pragma unroll
        for (int g = 0; g < 4; g++) acc[f][g] = (f32x4)(0.0f);

    for (int k0 = 0; k0 < DTRANK; k0 += 32) {
        const bf16x8 a0 = *(const bf16x8*)&dtr[(size_t)(m0 + srow) * DTRANK + k0 + sc];
        const bf16x8 a1 = *(const bf16x8*)&dtr[(size_t)(m0 + srow) * DTRANK + k0 + sc + 8];
        const bf16x8 b0 = *(const bf16x8*)&Wdtb[(size_t)(n0 + srow) * DTRANK + k0 + sc];
        const bf16x8 b1 = *(const bf16x8*)&Wdtb[(size_t)(n0 + srow) * DTRANK + k0 + sc + 8];
        __syncthreads();
        *(bf16x8*)&As[srow * G2RS + sc]     = a0;
        *(bf16x8*)&As[srow * G2RS + sc + 8] = a1;
        *(bf16x8*)&Bs[srow * G2RS + sc]     = b0;
        *(bf16x8*)&Bs[srow * G2RS + sc + 8] = b1;
        __syncthreads();

        bf16x8 a[4], b[4];
#pragma unroll
        for (int f = 0; f < 4; f++)
            a[f] = *(const bf16x8*)&As[(mw + f * 16 + r) * G2RS + quad * 8];
#pragma unroll
        for (int g = 0; g < 4; g++)
            b[g] = *(const bf16x8*)&Bs[(nw + g * 16 + r) * G2RS + quad * 8];
#pragma unroll
        for (int f = 0; f < 4; f++)
#pragma unroll
            for (int g = 0; g < 4; g++)
                acc[f][g] = __builtin_amdgcn_mfma_f32_16x16x32_bf16(a[f], b[g], acc[f][g], 0, 0, 0);
    }

#pragma unroll
    for (int f = 0; f < 4; f++) {
        const int row0 = m0 + mw + f * 16 + quad * 4;
#pragma unroll
        for (int g = 0; g < 4; g++) {
            const int col = n0 + nw + g * 16 + r;
            const float bv = bdt[col];
#pragma unroll
            for (int i = 0; i < 4; i++)
                deltab[(size_t)(row0 + i) * DI + col] = f2bf(softplus_fast(acc[f][g][i] + bv));
        }
    }
}

// ---------------------------------------------------------------------------
// Scan pass 1: per (b, chunk, d) chunk summary (P = prod dA, H = h_end), h=0.
// grid: BSZ*NC*8 = 1024 blocks. Compact BC rows staged in LDS.
// ---------------------------------------------------------------------------
__global__ __launch_bounds__(256) void scan_pass1(const float* __restrict__ x,
                                                  const unsigned short* __restrict__ deltab,
                                                  const float* __restrict__ BC,
                                                  const float* __restrict__ Alog,
                                                  float* __restrict__ Pb,
                                                  float* __restrict__ Hb) {
    __shared__ __align__(16) float Ls[CL * 16];
    const int bi   = blockIdx.x;
    const int b    = bi >> 9;
    const int c    = (bi >> 3) & 63;
    const int dblk = bi & 7;
    const int tid  = threadIdx.x;
    const int d    = dblk * 256 + tid;
    const int l0   = c * CL;
    const size_t row0 = (size_t)b * LSEQ + l0;

    if (tid < CL * 4) {
        const int l = tid >> 2, part = (tid & 3) * 4;
        *(float4*)&Ls[l * 16 + part] = *(const float4*)&BC[(row0 + l) * 16 + part];
    }

    float A[8], P[8], H[8];
#pragma unroll
    for (int n = 0; n < 8; n++) {
        A[n] = -__expf(Alog[d * 8 + n]);
        P[n] = 1.f;
        H[n] = 0.f;
    }
    __syncthreads();

#pragma unroll 4
    for (int l = 0; l < CL; l++) {
        const size_t row = row0 + l;
        const float dl = bf2f(deltab[row * DI + d]);
        const float xv = x[row * DI + d];
        const float du = dl * xv;
#pragma unroll
        for (int n = 0; n < 8; n++) {
            const float dA = __expf(dl * A[n]);
            H[n] = dA * H[n] + du * Ls[l * 16 + n];
            P[n] *= dA;
        }
    }
    const size_t base = ((size_t)(b * NC + c) * DI + d) * 8;
    *(float4*)&Pb[base]     = make_float4(P[0], P[1], P[2], P[3]);
    *(float4*)&Pb[base + 4] = make_float4(P[4], P[5], P[6], P[7]);
    *(float4*)&Hb[base]     = make_float4(H[0], H[1], H[2], H[3]);
    *(float4*)&Hb[base + 4] = make_float4(H[4], H[5], H[6], H[7]);
}

// ---------------------------------------------------------------------------
// Scan pass 2: combine NC chunk summaries -> h0 entering each chunk.
// One thread per (b, d, n) scalar chain: 32768 threads, coalesced.
// ---------------------------------------------------------------------------
__global__ __launch_bounds__(256) void scan_pass2(const float* __restrict__ Pb,
                                                  const float* __restrict__ Hb,
                                                  float* __restrict__ h0) {
    const int t   = blockIdx.x * 256 + threadIdx.x;  // 0..32767
    const int b   = t >> 14;
    const int rem = t & 16383;                       // d*8+n
    float h = 0.f;
#pragma unroll 4
    for (int c = 0; c < NC; c++) {
        const size_t base = (size_t)(b * NC + c) * (DI * 8) + rem;
        h0[base] = h;
        h = Pb[base] * h + Hb[base];
    }
}

// ---------------------------------------------------------------------------
// Scan pass 3: re-scan each chunk from h0, produce y. Compact BC in LDS.
// ---------------------------------------------------------------------------
__global__ __launch_bounds__(256) void scan_pass3(const float* __restrict__ x,
                                                  const unsigned short* __restrict__ deltab,
                                                  const float* __restrict__ BC,
                                                  const float* __restrict__ Alog,
                                                  const float* __restrict__ Dp,
                                                  const float* __restrict__ h0,
                                                  float* __restrict__ y) {
    __shared__ __align__(16) float Ls[CL * 16];
    const int bi   = blockIdx.x;
    const int b    = bi >> 9;
    const int c    = (bi >> 3) & 63;
    const int dblk = bi & 7;
    const int tid  = threadIdx.x;
    const int d    = dblk * 256 + tid;
    const int l0   = c * CL;
    const size_t row0 = (size_t)b * LSEQ + l0;

    if (tid < CL * 4) {
        const int l = tid >> 2, part = (tid & 3) * 4;
        *(float4*)&Ls[l * 16 + part] = *(const float4*)&BC[(row0 + l) * 16 + part];
    }

    float A[8], h[8];
    const size_t hbase = ((size_t)(b * NC + c) * DI + d) * 8;
    const float4 h0a = *(const float4*)&h0[hbase];
    const float4 h0b = *(const float4*)&h0[hbase + 4];
    h[0] = h0a.x; h[1] = h0a.y; h[2] = h0a.z; h[3] = h0a.w;
    h[4] = h0b.x; h[5] = h0b.y; h[6] = h0b.z; h[7] = h0b.w;
#pragma unroll
    for (int n = 0; n < 8; n++) A[n] = -__expf(Alog[d * 8 + n]);
    const float Dpar = Dp[d];
    __syncthreads();

#pragma unroll 4
    for (int l = 0; l < CL; l++) {
        const size_t row = row0 + l;
        const float dl = bf2f(deltab[row * DI + d]);
        const float xv = x[row * DI + d];
        const float du = dl * xv;
        float yv = 0.f;
#pragma unroll
        for (int n = 0; n < 8; n++) {
            const float dA = __expf(dl * A[n]);
            h[n] = dA * h[n] + du * Ls[l * 16 + n];
            yv += h[n] * Ls[l * 16 + 8 + n];
        }
        y[row * DI + d] = yv + xv * Dpar;
    }
}

// ---------------------------------------------------------------------------
extern "C" void kernel_launch(void* const* d_in, const int* in_sizes, int n_in,
                              void* d_out, int out_size, void* d_ws, size_t ws_size,
                              hipStream_t stream) {
    const float* x    = (const float*)d_in[0];
    const float* Wx   = (const float*)d_in[1];
    const float* Wdt  = (const float*)d_in[2];
    const float* bdt  = (const float*)d_in[3];
    const float* Alog = (const float*)d_in[4];
    const float* Dp   = (const float*)d_in[5];
    float* y = (float*)d_out;

    // Workspace (float offsets). deltab aliases partb (dead after reduce1).
    float* ws = (float*)d_ws;
    unsigned short* partb  = (unsigned short*)ws;        // 8*4096*288 bf16
    unsigned short* deltab = (unsigned short*)ws;        // alias
    float* BC = ws + 4718592;
    float* Pb = ws + 4784128;
    float* Hb = ws + 6881280;
    float* h0 = ws + 8978432;
    unsigned short* Wxb  = (unsigned short*)(ws + 11075584);
    unsigned short* Wdtb = (unsigned short*)(ws + 11370496);
    unsigned short* dtr  = (unsigned short*)(ws + 11632640);

    dim3 blk(256);
    hipLaunchKernelGGL(convert_w, dim3((NWXP + NWDT) / 4 / 256), blk, 0, stream,
                       Wx, Wdt, Wxb, Wdtb);
    hipLaunchKernelGGL(gemm1_mfma, dim3(64, KSPLIT), blk, 0, stream, x, Wxb, partb);
    hipLaunchKernelGGL(reduce1, dim3(4096 * 72 / 256), blk, 0, stream, partb, dtr, BC);
    hipLaunchKernelGGL(gemm2_mfma, dim3(16, 32), blk, 0, stream, dtr, Wdtb, bdt, deltab);
    hipLaunchKernelGGL(scan_pass1, dim3(BSZ * NC * 8), blk, 0, stream, x, deltab, BC, Alog, Pb, Hb);
    hipLaunchKernelGGL(scan_pass2, dim3(128), blk, 0, stream, Pb, Hb, h0);
    hipLaunchKernelGGL(scan_pass3, dim3(BSZ * NC * 8), blk, 0, stream, x, deltab, BC, Alog, Dp, h0, y);
}